// Round 7
// baseline (824.066 us; speedup 1.0000x reference)
//
#include <hip/hip_runtime.h>

#define N_TOK 4096
#define DM 256
#define NH 8
#define DK 32

using u16 = unsigned short;
using u32 = unsigned int;
using i64 = long long;
typedef float f32x4 __attribute__((ext_vector_type(4)));   // native vec for nontemporal

__device__ __forceinline__ float bf2f(u16 u){ return __uint_as_float(((u32)u) << 16); }
__device__ __forceinline__ u16 f2bf(float f){
    u32 x = __float_as_uint(f);
    x += 0x7fffu + ((x >> 16) & 1u);   // round-to-nearest-even (finite values)
    return (u16)(x >> 16);
}

// ---- per-query segment bounds (batch sorted; int32 or int64 probed) ----
__global__ __launch_bounds__(256)
void bounds_kernel(const void* __restrict__ batch_q, const void* __restrict__ batch_kv,
                   int2* __restrict__ bounds)
{
    int q = blockIdx.x * 256 + threadIdx.x;
    const int* kv32 = (const int*)batch_kv;
    const i64* kv64 = (const i64*)batch_kv;
    bool is64 = (kv32[N_TOK - 1] == 0);   // sorted max > 0 if int32; zero hi-word if int64
    int s = is64 ? (int)((const i64*)batch_q)[q] : ((const int*)batch_q)[q];
    int lo = 0, hi = N_TOK;               // lower_bound(s)
    while (lo < hi){ int m = (lo + hi) >> 1; int v = is64 ? (int)kv64[m] : kv32[m]; if (v < s) lo = m + 1; else hi = m; }
    int lo2 = lo, hi2 = N_TOK;            // upper_bound(s)
    while (lo2 < hi2){ int m = (lo2 + hi2) >> 1; int v = is64 ? (int)kv64[m] : kv32[m]; if (v <= s) lo2 = m + 1; else hi2 = m; }
    bounds[q] = make_int2(lo, lo2);
}

// ---- streaming zero fill of the attn region (like fillBufferAligned) ----
__global__ __launch_bounds__(256)
void fill_zero(f32x4* __restrict__ p, unsigned long long n4)
{
    unsigned long long i = (unsigned long long)blockIdx.x * 256 + threadIdx.x;
    unsigned long long stride = (unsigned long long)gridDim.x * 256;
    f32x4 z = {0.f, 0.f, 0.f, 0.f};
    for (; i < n4; i += stride)
        __builtin_nontemporal_store(z, &p[i]);
}

// out[r][c] = sum_d x[r][d] * W[c][d] + b[c]   (torch Linear: x @ W.T + b)
// 16 rows per block; x reads are wave-uniform (scalar path); W row per thread.
template<int OUT_BF16>
__global__ __launch_bounds__(256)
void proj_kernel(const float* __restrict__ x, const float* __restrict__ W,
                 const float* __restrict__ bias, void* __restrict__ outv)
{
    const int ROWS = 16;
    int row0 = blockIdx.x * ROWS;
    int c = threadIdx.x;
    float acc[ROWS];
    float bv = bias[c];
#pragma unroll
    for (int r = 0; r < ROWS; ++r) acc[r] = bv;

    const float4* Wv = (const float4*)(W + (size_t)c * DM);
    for (int i = 0; i < DM / 4; ++i){
        float4 w = Wv[i];
        int d0 = i * 4;
#pragma unroll
        for (int r = 0; r < ROWS; ++r){
            const float* xr = x + (size_t)(row0 + r) * DM + d0;  // uniform
            acc[r] += xr[0] * w.x + xr[1] * w.y + xr[2] * w.z + xr[3] * w.w;
        }
    }
#pragma unroll
    for (int r = 0; r < ROWS; ++r){
        size_t idx = (size_t)(row0 + r) * DM + c;
        if (OUT_BF16) ((u16*)outv)[idx] = f2bf(acc[r]);
        else          ((float*)outv)[idx] = acc[r];
    }
}

// Fused K+V projection from x_kv; writes bf16 K and V workspace tensors.
__global__ __launch_bounds__(256)
void proj_kv_kernel(const float* __restrict__ x, const float* __restrict__ Wk,
                    const float* __restrict__ bk, const float* __restrict__ Wv,
                    const float* __restrict__ bv, u16* __restrict__ Kp,
                    u16* __restrict__ Vp)
{
    const int ROWS = 16;
    int row0 = blockIdx.x * ROWS;
    int c = threadIdx.x;
    float acck[ROWS], accv[ROWS];
    float bkv = bk[c], bvv = bv[c];
#pragma unroll
    for (int r = 0; r < ROWS; ++r){ acck[r] = bkv; accv[r] = bvv; }

    const float4* Wk4 = (const float4*)(Wk + (size_t)c * DM);
    const float4* Wv4 = (const float4*)(Wv + (size_t)c * DM);
    for (int i = 0; i < DM / 4; ++i){
        float4 wk = Wk4[i];
        float4 wv = Wv4[i];
        int d0 = i * 4;
#pragma unroll
        for (int r = 0; r < ROWS; ++r){
            const float* xr = x + (size_t)(row0 + r) * DM + d0;  // uniform
            float x0 = xr[0], x1 = xr[1], x2 = xr[2], x3 = xr[3];
            acck[r] += x0 * wk.x + x1 * wk.y + x2 * wk.z + x3 * wk.w;
            accv[r] += x0 * wv.x + x1 * wv.y + x2 * wv.z + x3 * wv.w;
        }
    }
#pragma unroll
    for (int r = 0; r < ROWS; ++r){
        size_t idx = (size_t)(row0 + r) * DM + c;
        Kp[idx] = f2bf(acck[r]);
        Vp[idx] = f2bf(accv[r]);
    }
}

// One block per (query q, head h). Bounds precomputed. attn region pre-zeroed:
// writes ONLY the in-segment probs [lo,hi) + the O accumulator.
__global__ __launch_bounds__(256)
void attn_compute(const float* __restrict__ Q, const u16* __restrict__ K,
                  const u16* __restrict__ V, const int2* __restrict__ bounds,
                  float* __restrict__ attn, float* __restrict__ O)
{
    __shared__ float sc[N_TOK];    // unnormalized probs
    __shared__ float qs[DK];
    __shared__ float red[8];
    __shared__ float Osh[DK];

    int q = blockIdx.x, h = blockIdx.y, tid = threadIdx.x;
    int2 bnd = bounds[q];          // wave-uniform -> scalar load
    const int lo = bnd.x, hi = bnd.y;

    if (tid < DK){ qs[tid] = Q[(size_t)q * DM + h * DK + tid]; Osh[tid] = 0.f; }
    __syncthreads();

    const float scale = 0.17677669529663687f;   // 1/sqrt(32)

    // ---- scores + local max ----
    float lmax = -1e30f;
    for (int k = lo + tid; k < hi; k += 256){
        const uint4* kr = (const uint4*)(K + (size_t)k * DM + h * DK);
        float dot = 0.f;
#pragma unroll
        for (int i = 0; i < 4; ++i){
            uint4 p = kr[i];
            dot += qs[i*8+0]*bf2f((u16)p.x) + qs[i*8+1]*bf2f((u16)(p.x>>16));
            dot += qs[i*8+2]*bf2f((u16)p.y) + qs[i*8+3]*bf2f((u16)(p.y>>16));
            dot += qs[i*8+4]*bf2f((u16)p.z) + qs[i*8+5]*bf2f((u16)(p.z>>16));
            dot += qs[i*8+6]*bf2f((u16)p.w) + qs[i*8+7]*bf2f((u16)(p.w>>16));
        }
        dot *= scale;
        sc[k - lo] = dot;
        lmax = fmaxf(lmax, dot);
    }
#pragma unroll
    for (int off = 32; off; off >>= 1) lmax = fmaxf(lmax, __shfl_xor(lmax, off, 64));
    if ((tid & 63) == 0) red[tid >> 6] = lmax;
    __syncthreads();
    float m = fmaxf(fmaxf(red[0], red[1]), fmaxf(red[2], red[3]));

    // ---- exp + local sum ----
    float lsum = 0.f;
    for (int k = lo + tid; k < hi; k += 256){
        float p = __expf(sc[k - lo] - m);
        sc[k - lo] = p;
        lsum += p;
    }
#pragma unroll
    for (int off = 32; off; off >>= 1) lsum += __shfl_xor(lsum, off, 64);
    if ((tid & 63) == 0) red[4 + (tid >> 6)] = lsum;
    __syncthreads();
    float sum = red[4] + red[5] + red[6] + red[7];
    float inv = (sum > 0.f) ? (1.0f / sum) : 0.f;   // never inf/NaN

    // ---- write in-segment probs only (region pre-zeroed) ----
    float* arow = attn + ((size_t)h * N_TOK + q) * N_TOK;
    for (int k = lo + tid; k < hi; k += 256)
        arow[k] = sc[k - lo] * inv;

    // ---- O[q, h*32+d] = sum_k p_k * V[k, h*32+d] ----
    // thread = (g, d2): g = k-group (16), d2 = bf16 pair index (16)
    int d2 = tid & 15;
    int g  = tid >> 4;
    float p0 = 0.f, p1 = 0.f;
    for (int k = lo + g; k < hi; k += 16){
        u32 pv = *(const u32*)(V + (size_t)k * DM + h * DK + 2 * d2);
        float p = sc[k - lo];
        p0 += p * bf2f((u16)pv);
        p1 += p * bf2f((u16)(pv >> 16));
    }
    // reduce across the 4 g-groups within each wave (lanes differ in bits 4..5)
    p0 += __shfl_xor(p0, 16, 64); p0 += __shfl_xor(p0, 32, 64);
    p1 += __shfl_xor(p1, 16, 64); p1 += __shfl_xor(p1, 32, 64);
    if ((tid & 63) < 16){
        atomicAdd(&Osh[2 * d2 + 0], p0);
        atomicAdd(&Osh[2 * d2 + 1], p1);
    }
    __syncthreads();
    if (tid < DK) O[(size_t)q * DM + h * DK + tid] = Osh[tid] * inv;
}

extern "C" void kernel_launch(void* const* d_in, const int* in_sizes, int n_in,
                              void* d_out, int out_size, void* d_ws, size_t ws_size,
                              hipStream_t stream)
{
    const float* x_q  = (const float*)d_in[0];
    const float* x_kv = (const float*)d_in[1];
    const void* batch_q  = d_in[2];
    const void* batch_kv = d_in[3];
    const float* Wq = (const float*)d_in[4];
    const float* bq = (const float*)d_in[5];
    const float* Wk = (const float*)d_in[6];
    const float* bk = (const float*)d_in[7];
    const float* Wv = (const float*)d_in[8];
    const float* bv = (const float*)d_in[9];
    const float* Wo = (const float*)d_in[10];
    const float* bo = (const float*)d_in[11];

    char* ws = (char*)d_ws;
    float* Q  = (float*)ws;                                 // 4 MB fp32
    u16*   Kp = (u16*)(ws + (size_t)4 * 1024 * 1024);       // 2 MB bf16
    u16*   Vp = (u16*)(ws + (size_t)6 * 1024 * 1024);       // 2 MB bf16
    float* O  = (float*)(ws + (size_t)8 * 1024 * 1024);     // 4 MB fp32
    int2* bounds = (int2*)(ws + (size_t)12 * 1024 * 1024);  // 32 KB

    float* out  = (float*)d_out;                            // [4096,256] fp32
    float* attn = out + (size_t)N_TOK * DM;                 // [8,4096,4096] fp32

    // independent streaming zero of the attn region first (covers all rows)
    unsigned long long n4 = (unsigned long long)NH * N_TOK * N_TOK / 4;
    fill_zero<<<8192, 256, 0, stream>>>((f32x4*)attn, n4);

    bounds_kernel<<<N_TOK / 256, 256, 0, stream>>>(batch_q, batch_kv, bounds);
    proj_kernel<0><<<N_TOK/16, 256, 0, stream>>>(x_q,  Wq, bq, Q);
    proj_kv_kernel<<<N_TOK/16, 256, 0, stream>>>(x_kv, Wk, bk, Wv, bv, Kp, Vp);
    attn_compute<<<dim3(N_TOK, NH), 256, 0, stream>>>(Q, Kp, Vp, bounds, attn, O);
    proj_kernel<0><<<N_TOK/16, 256, 0, stream>>>((const float*)O, Wo, bo, out);
}

// Round 9
// 715.609 us; speedup vs baseline: 1.1516x; 1.1516x over previous
//
#include <hip/hip_runtime.h>

#define N_TOK 4096
#define DM 256
#define NH 8
#define DK 32

using u16 = unsigned short;
using u32 = unsigned int;
using i64 = long long;
typedef float f32x4 __attribute__((ext_vector_type(4)));   // native vec for nontemporal

__device__ __forceinline__ float bf2f(u16 u){ return __uint_as_float(((u32)u) << 16); }
__device__ __forceinline__ u16 f2bf(float f){
    u32 x = __float_as_uint(f);
    x += 0x7fffu + ((x >> 16) & 1u);   // round-to-nearest-even (finite values)
    return (u16)(x >> 16);
}

// ---- per-query segment bounds (batch sorted; int32 or int64 probed) ----
__global__ __launch_bounds__(256)
void bounds_kernel(const void* __restrict__ batch_q, const void* __restrict__ batch_kv,
                   int2* __restrict__ bounds)
{
    int q = blockIdx.x * 256 + threadIdx.x;
    const int* kv32 = (const int*)batch_kv;
    const i64* kv64 = (const i64*)batch_kv;
    bool is64 = (kv32[N_TOK - 1] == 0);   // sorted max > 0 if int32; zero hi-word if int64
    int s = is64 ? (int)((const i64*)batch_q)[q] : ((const int*)batch_q)[q];
    int lo = 0, hi = N_TOK;               // lower_bound(s)
    while (lo < hi){ int m = (lo + hi) >> 1; int v = is64 ? (int)kv64[m] : kv32[m]; if (v < s) lo = m + 1; else hi = m; }
    int lo2 = lo, hi2 = N_TOK;            // upper_bound(s)
    while (lo2 < hi2){ int m = (lo2 + hi2) >> 1; int v = is64 ? (int)kv64[m] : kv32[m]; if (v <= s) lo2 = m + 1; else hi2 = m; }
    bounds[q] = make_int2(lo, lo2);
}

// out[r][c] = sum_d x[r][d] * W[c][d] + b[c]   (torch Linear: x @ W.T + b)
// 16 rows per block; x reads are wave-uniform (scalar path); W row per thread.
template<int OUT_BF16>
__global__ __launch_bounds__(256)
void proj_kernel(const float* __restrict__ x, const float* __restrict__ W,
                 const float* __restrict__ bias, void* __restrict__ outv)
{
    const int ROWS = 16;
    int row0 = blockIdx.x * ROWS;
    int c = threadIdx.x;
    float acc[ROWS];
    float bv = bias[c];
#pragma unroll
    for (int r = 0; r < ROWS; ++r) acc[r] = bv;

    const float4* Wv = (const float4*)(W + (size_t)c * DM);
    for (int i = 0; i < DM / 4; ++i){
        float4 w = Wv[i];
        int d0 = i * 4;
#pragma unroll
        for (int r = 0; r < ROWS; ++r){
            const float* xr = x + (size_t)(row0 + r) * DM + d0;  // uniform
            acc[r] += xr[0] * w.x + xr[1] * w.y + xr[2] * w.z + xr[3] * w.w;
        }
    }
#pragma unroll
    for (int r = 0; r < ROWS; ++r){
        size_t idx = (size_t)(row0 + r) * DM + c;
        if (OUT_BF16) ((u16*)outv)[idx] = f2bf(acc[r]);
        else          ((float*)outv)[idx] = acc[r];
    }
}

// Fused K+V projection from x_kv; writes bf16 K and V workspace tensors.
__global__ __launch_bounds__(256)
void proj_kv_kernel(const float* __restrict__ x, const float* __restrict__ Wk,
                    const float* __restrict__ bk, const float* __restrict__ Wv,
                    const float* __restrict__ bv, u16* __restrict__ Kp,
                    u16* __restrict__ Vp)
{
    const int ROWS = 16;
    int row0 = blockIdx.x * ROWS;
    int c = threadIdx.x;
    float acck[ROWS], accv[ROWS];
    float bkv = bk[c], bvv = bv[c];
#pragma unroll
    for (int r = 0; r < ROWS; ++r){ acck[r] = bkv; accv[r] = bvv; }

    const float4* Wk4 = (const float4*)(Wk + (size_t)c * DM);
    const float4* Wv4 = (const float4*)(Wv + (size_t)c * DM);
    for (int i = 0; i < DM / 4; ++i){
        float4 wk = Wk4[i];
        float4 wv = Wv4[i];
        int d0 = i * 4;
#pragma unroll
        for (int r = 0; r < ROWS; ++r){
            const float* xr = x + (size_t)(row0 + r) * DM + d0;  // uniform
            float x0 = xr[0], x1 = xr[1], x2 = xr[2], x3 = xr[3];
            acck[r] += x0 * wk.x + x1 * wk.y + x2 * wk.z + x3 * wk.w;
            accv[r] += x0 * wv.x + x1 * wv.y + x2 * wv.z + x3 * wv.w;
        }
    }
#pragma unroll
    for (int r = 0; r < ROWS; ++r){
        size_t idx = (size_t)(row0 + r) * DM + c;
        Kp[idx] = f2bf(acck[r]);
        Vp[idx] = f2bf(accv[r]);
    }
}

// One block per (query q, head h). Bounds precomputed. Writes the FULL attn
// row (zeros outside segment) with nontemporal stores (bypass L2 so K/V stay
// resident), ordered AFTER the PV load phase so stores don't block PV vmcnt.
__global__ __launch_bounds__(256)
void attn_kernel(const float* __restrict__ Q, const u16* __restrict__ K,
                 const u16* __restrict__ V, const int2* __restrict__ bounds,
                 float* __restrict__ attn, float* __restrict__ O)
{
    __shared__ float sc[N_TOK];    // unnormalized probs
    __shared__ float qs[DK];
    __shared__ float red[8];
    __shared__ float Osh[DK];

    int q = blockIdx.x, h = blockIdx.y, tid = threadIdx.x;
    int2 bnd = bounds[q];          // wave-uniform -> scalar load
    const int lo = bnd.x, hi = bnd.y;

    if (tid < DK){ qs[tid] = Q[(size_t)q * DM + h * DK + tid]; Osh[tid] = 0.f; }
    __syncthreads();

    const float scale = 0.17677669529663687f;   // 1/sqrt(32)

    // ---- scores + local max ----
    float lmax = -1e30f;
    for (int k = lo + tid; k < hi; k += 256){
        const uint4* kr = (const uint4*)(K + (size_t)k * DM + h * DK);
        float dot = 0.f;
#pragma unroll
        for (int i = 0; i < 4; ++i){
            uint4 p = kr[i];
            dot += qs[i*8+0]*bf2f((u16)p.x) + qs[i*8+1]*bf2f((u16)(p.x>>16));
            dot += qs[i*8+2]*bf2f((u16)p.y) + qs[i*8+3]*bf2f((u16)(p.y>>16));
            dot += qs[i*8+4]*bf2f((u16)p.z) + qs[i*8+5]*bf2f((u16)(p.z>>16));
            dot += qs[i*8+6]*bf2f((u16)p.w) + qs[i*8+7]*bf2f((u16)(p.w>>16));
        }
        dot *= scale;
        sc[k - lo] = dot;
        lmax = fmaxf(lmax, dot);
    }
#pragma unroll
    for (int off = 32; off; off >>= 1) lmax = fmaxf(lmax, __shfl_xor(lmax, off, 64));
    if ((tid & 63) == 0) red[tid >> 6] = lmax;
    __syncthreads();
    float m = fmaxf(fmaxf(red[0], red[1]), fmaxf(red[2], red[3]));

    // ---- exp + local sum ----
    float lsum = 0.f;
    for (int k = lo + tid; k < hi; k += 256){
        float p = __expf(sc[k - lo] - m);
        sc[k - lo] = p;
        lsum += p;
    }
#pragma unroll
    for (int off = 32; off; off >>= 1) lsum += __shfl_xor(lsum, off, 64);
    if ((tid & 63) == 0) red[4 + (tid >> 6)] = lsum;
    __syncthreads();
    float sum = red[4] + red[5] + red[6] + red[7];
    float inv = (sum > 0.f) ? (1.0f / sum) : 0.f;   // never inf/NaN

    // ---- PV first (loads), then the bulk store stream ----
    // thread = (g, d2): g = k-group (16), d2 = bf16 pair index (16)
    int d2 = tid & 15;
    int g  = tid >> 4;
    float p0 = 0.f, p1 = 0.f;
    for (int k = lo + g; k < hi; k += 16){
        u32 pv = *(const u32*)(V + (size_t)k * DM + h * DK + 2 * d2);
        float p = sc[k - lo];
        p0 += p * bf2f((u16)pv);
        p1 += p * bf2f((u16)(pv >> 16));
    }
    p0 += __shfl_xor(p0, 16, 64); p0 += __shfl_xor(p0, 32, 64);
    p1 += __shfl_xor(p1, 16, 64); p1 += __shfl_xor(p1, 32, 64);
    if ((tid & 63) < 16){
        atomicAdd(&Osh[2 * d2 + 0], p0);
        atomicAdd(&Osh[2 * d2 + 1], p1);
    }

    // ---- write full attn row (zeros outside segment), nontemporal float4 ----
    f32x4* arow4 = (f32x4*)(attn + ((size_t)h * N_TOK + q) * N_TOK);
#pragma unroll
    for (int i = 0; i < N_TOK / 1024; ++i){
        int t = i * 256 + tid;         // float4 index 0..1023
        int k0 = 4 * t;
        f32x4 w;
        w.x = (k0 + 0 >= lo && k0 + 0 < hi) ? sc[k0 + 0 - lo] * inv : 0.f;
        w.y = (k0 + 1 >= lo && k0 + 1 < hi) ? sc[k0 + 1 - lo] * inv : 0.f;
        w.z = (k0 + 2 >= lo && k0 + 2 < hi) ? sc[k0 + 2 - lo] * inv : 0.f;
        w.w = (k0 + 3 >= lo && k0 + 3 < hi) ? sc[k0 + 3 - lo] * inv : 0.f;
        __builtin_nontemporal_store(w, &arow4[t]);
    }

    __syncthreads();
    if (tid < DK) O[(size_t)q * DM + h * DK + tid] = Osh[tid] * inv;
}

extern "C" void kernel_launch(void* const* d_in, const int* in_sizes, int n_in,
                              void* d_out, int out_size, void* d_ws, size_t ws_size,
                              hipStream_t stream)
{
    const float* x_q  = (const float*)d_in[0];
    const float* x_kv = (const float*)d_in[1];
    const void* batch_q  = d_in[2];
    const void* batch_kv = d_in[3];
    const float* Wq = (const float*)d_in[4];
    const float* bq = (const float*)d_in[5];
    const float* Wk = (const float*)d_in[6];
    const float* bk = (const float*)d_in[7];
    const float* Wv = (const float*)d_in[8];
    const float* bv = (const float*)d_in[9];
    const float* Wo = (const float*)d_in[10];
    const float* bo = (const float*)d_in[11];

    char* ws = (char*)d_ws;
    float* Q  = (float*)ws;                                 // 4 MB fp32
    u16*   Kp = (u16*)(ws + (size_t)4 * 1024 * 1024);       // 2 MB bf16
    u16*   Vp = (u16*)(ws + (size_t)6 * 1024 * 1024);       // 2 MB bf16
    float* O  = (float*)(ws + (size_t)8 * 1024 * 1024);     // 4 MB fp32
    int2* bounds = (int2*)(ws + (size_t)12 * 1024 * 1024);  // 32 KB

    float* out  = (float*)d_out;                            // [4096,256] fp32
    float* attn = out + (size_t)N_TOK * DM;                 // [8,4096,4096] fp32

    bounds_kernel<<<N_TOK / 256, 256, 0, stream>>>(batch_q, batch_kv, bounds);
    proj_kernel<0><<<N_TOK/16, 256, 0, stream>>>(x_q,  Wq, bq, Q);
    proj_kv_kernel<<<N_TOK/16, 256, 0, stream>>>(x_kv, Wk, bk, Wv, bv, Kp, Vp);
    attn_kernel<<<dim3(N_TOK, NH), 256, 0, stream>>>(Q, Kp, Vp, bounds, attn, O);
    proj_kernel<0><<<N_TOK/16, 256, 0, stream>>>((const float*)O, Wo, bo, out);
}